// Round 7
// baseline (181.279 us; speedup 1.0000x reference)
//
#include <hip/hip_runtime.h>
#include <math.h>

// Shapes (fixed by the problem)
#define Hn 8
#define Sn 1024
#define Dn 64
#define KG 10
#define KS 2                    // k-splits per (q-block, head)

// Bias tables: dist in [0,10), energy in [0,5)
#define TN 2048
#define RD 10.25f
#define RE 5.125f

typedef __attribute__((ext_vector_type(8))) short bf16x8;
typedef __attribute__((ext_vector_type(4))) float f32x4;
typedef unsigned short u16;
typedef unsigned int u32;

__device__ inline float bf2f(u16 u) {
    union { u32 i; float f; } v;
    v.i = ((u32)u) << 16;
    return v.f;
}

__device__ inline u16 f2bf(float f) {
    union { float f; u32 i; } v;
    v.f = f;
    u32 i = v.i;
    return (u16)((i + 0x7FFFu + ((i >> 16) & 1u)) >> 16);   // RNE
}

// ---------------------------------------------------------------------------
// RBF (10 gaussians) -> 10x10 MLP (exact gelu) -> scalar, all f32.
// ---------------------------------------------------------------------------
__device__ float bias_eval(float x,
                           const float* __restrict__ mu, const float* __restrict__ sg,
                           const float* __restrict__ bb,
                           const float* __restrict__ W1, const float* __restrict__ b1,
                           const float* __restrict__ W2, const float* __restrict__ b2) {
    const float inv_s2pi = 0.39894228040143267794f;
    float psi[KG];
#pragma unroll
    for (int k = 0; k < KG; k++) {
        float s = sg[k];
        float z = (x + bb[k] - mu[k]) / s;
        psi[k] = __expf(-0.5f * z * z) * (inv_s2pi / s);
    }
    float out = b2[0];
#pragma unroll
    for (int l = 0; l < KG; l++) {
        float a = b1[l];
#pragma unroll
        for (int k = 0; k < KG; k++) a += psi[k] * W1[l * KG + k];
        float g = 0.5f * a * (1.0f + erff(a * 0.70710678118654752440f));
        out += g * W2[l];
    }
    return out;
}

// ---------------------------------------------------------------------------
// Kernel A: interpolation tables. Entry i: lo16 = bf16(f(x_i)),
// hi16 = bf16(f(x_{i+1}) - f(x_i)). [0,TN) dist, [TN,2TN) energy.
// ---------------------------------------------------------------------------
__global__ __launch_bounds__(256) void build_tables_kernel(
    const float* __restrict__ muD, const float* __restrict__ sgD, const float* __restrict__ bD,
    const float* __restrict__ muE, const float* __restrict__ sgE, const float* __restrict__ bE,
    const float* __restrict__ W1, const float* __restrict__ b1,
    const float* __restrict__ W2, const float* __restrict__ b2,
    u32* __restrict__ tab)
{
    int id = blockIdx.x * 256 + threadIdx.x;   // 0 .. 4095
    int which = (id >= TN);
    int idx = id & (TN - 1);
    float h = (which ? RE : RD) / (float)TN;
    float x0 = idx * h;
    float v0, v1;
    if (which) {
        v0 = bias_eval(x0,     muE, sgE, bE, W1, b1, W2, b2);
        v1 = bias_eval(x0 + h, muE, sgE, bE, W1, b1, W2, b2);
    } else {
        v0 = bias_eval(x0,     muD, sgD, bD, W1, b1, W2, b2);
        v1 = bias_eval(x0 + h, muD, sgD, bD, W1, b1, W2, b2);
    }
    tab[id] = (u32)f2bf(v0) | ((u32)f2bf(v1 - v0) << 16);
}

// ---------------------------------------------------------------------------
// Kernel B: small prepass.
//  WGs [0,1024)     : Q,K f32 -> bf16 (float4 granularity).
//  WGs [1024,1152)  : V -> bf16 transpose via LDS tile (coalesced both sides),
//                     layout [h][d][s'] with MFMA k-perm:
//                     s' = t*32+q*8+j  <->  s = t*32+q*4+(j&3)+16*(j>>2).
// ---------------------------------------------------------------------------
__global__ __launch_bounds__(256) void prep_kernel(
    const float* __restrict__ Q, const float* __restrict__ K, const float* __restrict__ V,
    u16* __restrict__ Qb, u16* __restrict__ Kb, u16* __restrict__ VTi)
{
    __shared__ float tile[64][68];
    const int wg = blockIdx.x, tid = threadIdx.x;

    if (wg < 1024) {
        int i = wg * 256 + tid;                  // 0 .. 262143 float4 units
        int arr = i >> 17;                        // 0 = Q, 1 = K
        i &= (1 << 17) - 1;
        float4 v = ((const float4*)(arr ? K : Q))[i];
        ushort4 o;
        o.x = f2bf(v.x); o.y = f2bf(v.y); o.z = f2bf(v.z); o.w = f2bf(v.w);
        ((ushort4*)(arr ? Kb : Qb))[i] = o;
    } else {
        const int b  = wg - 1024;                // 0..127
        const int h  = b >> 4;
        const int s0 = (b & 15) * 64;
        const int rr = tid >> 4, cc = (tid & 15) * 4;
        const float* Vh = V + ((size_t)h * Sn + s0) * Dn;
#pragma unroll
        for (int i = 0; i < 4; i++) {
            float4 v = *(const float4*)(Vh + (size_t)(i * 16 + rr) * Dn + cc);
            tile[i * 16 + rr][cc]     = v.x;
            tile[i * 16 + rr][cc + 1] = v.y;
            tile[i * 16 + rr][cc + 2] = v.z;
            tile[i * 16 + rr][cc + 3] = v.w;
        }
        __syncthreads();
        u16* dst = VTi + (size_t)h * Dn * Sn + s0;
#pragma unroll
        for (int i = 0; i < 4; i++) {
            const int d = i * 16 + rr;
            u16 tmp[4];
#pragma unroll
            for (int j2 = 0; j2 < 4; j2++) {
                int sp = cc + j2;                // s' in 0..63
                int q = (sp >> 3) & 3, j = sp & 7;
                int s = (sp & ~31) + q * 4 + (j & 3) + ((j >> 2) << 4);
                tmp[j2] = f2bf(tile[s][d]);
            }
            ushort4 o = {tmp[0], tmp[1], tmp[2], tmp[3]};
            *(ushort4*)(dst + (size_t)d * Sn + cc) = o;
        }
    }
}

// ---------------------------------------------------------------------------
// Kernel C: k-split fused attention partials.
// Grid (S/16, Hn, KS) = 1024 WGs, 256 thr = 4 waves; WG (qb,h,ks) handles
// 16 q-rows x 512 k-cols; wave w covers 128 cols = 4 tiles of 32.
// Per tile: D/E/M loaded DIRECTLY in S^T accumulator layout (float4/int4),
// lerp through LDS tables, fixed-max exp (no offset — scores bounded ~|70|),
// QK^T and PV MFMAs. D/E manually prefetched 2-deep (forces outstanding
// loads into dedicated VGPRs). Partial O (unnormalized) + partial l -> ws;
// fixed max ==> partials combine by plain sum.
// LDS = union(16 KB tables, 17.7 KB epilogue). VGPR target ~120 @ (256,4).
// ---------------------------------------------------------------------------
__global__ __launch_bounds__(256, 4) void attn_part_kernel(
    const u16* __restrict__ Qb, const u16* __restrict__ Kb, const u16* __restrict__ VTi,
    const float* __restrict__ Dm, const float* __restrict__ Em, const int* __restrict__ Mk,
    const u32* __restrict__ gtab,
    float* __restrict__ Opart, float* __restrict__ Lpart)
{
    __shared__ union {
        u32 tab[2 * TN];                                     // k-loop (16 KB)
        struct { float O[4][16][68]; float L[4][16]; } f;    // epilogue (17.7 KB)
    } sU;

    const int tid = threadIdx.x;
    {   // stage tables: 1024 uint4 over 256 threads
        const uint4* g4 = (const uint4*)gtab;
        uint4* s4 = (uint4*)sU.tab;
#pragma unroll
        for (int i = 0; i < 4; i++) s4[tid + 256 * i] = g4[tid + 256 * i];
    }
    __syncthreads();

    const int qb   = blockIdx.x;
    const int h    = blockIdx.y;
    const int ks   = blockIdx.z;
    const int q0   = qb * 16;
    const int wave = tid >> 6;
    const int lane = tid & 63;
    const int quad = lane >> 4;
    const int l16  = lane & 15;

    const u16* Qh = Qb  + (size_t)h * Sn * Dn;
    const u16* Kh = Kb  + (size_t)h * Sn * Dn;
    const u16* Vh = VTi + (size_t)h * Dn * Sn;
    const size_t rowoff = ((size_t)h * Sn + q0 + l16) * Sn;  // this lane's q-row
    const float* Dr = Dm + rowoff;
    const float* Er = Em + rowoff;
    const int*   Mr = Mk + rowoff;

    const float invhD = (float)TN / RD;
    const float invhE = (float)TN / RE;
    const float scale = 0.08838834764831845f;    // 1/sqrt(2*64)

    // Persistent Q B-fragments: B[n=l16][k=quad*8+j]
    const bf16x8 bQ0 = *(const bf16x8*)(Qh + (q0 + l16) * Dn + quad * 8);
    const bf16x8 bQ1 = *(const bf16x8*)(Qh + (q0 + l16) * Dn + 32 + quad * 8);

    f32x4 O0 = {0.f, 0.f, 0.f, 0.f}, O1 = O0, O2 = O0, O3 = O0;
    float l_r = 0.f;

    const int kbase = ks * (Sn / KS) + wave * 128;
    const u16* krb = Kh + (size_t)l16 * Dn + quad * 8;
    const u16* vrb = Vh + quad * 8;

    // 2-deep prefetch buffers for the big D/E stream (S^T layout)
    float4 pD0[2], pD1[2], pE0[2], pE1[2];
    {
        const int c = kbase + quad * 4;
        pD0[0] = *(const float4*)(Dr + c);
        pD1[0] = *(const float4*)(Dr + c + 16);
        pE0[0] = *(const float4*)(Er + c);
        pE1[0] = *(const float4*)(Er + c + 16);
    }

#pragma unroll
    for (int t = 0; t < 4; t++) {
        const int cur = t & 1, nxt = cur ^ 1;
        const int k0 = kbase + t * 32;

        if (t < 3) {   // prefetch next tile's D/E
            const int c = k0 + 32 + quad * 4;
            pD0[nxt] = *(const float4*)(Dr + c);
            pD1[nxt] = *(const float4*)(Dr + c + 16);
            pE0[nxt] = *(const float4*)(Er + c);
            pE1[nxt] = *(const float4*)(Er + c + 16);
        }

        // mask (all-ones in practice; consumed late, latency-tolerant)
        const int4 m0 = *(const int4*)(Mr + k0 + quad * 4);
        const int4 m1 = *(const int4*)(Mr + k0 + 16 + quad * 4);

        // K A-fragments (L2-resident stream)
        const u16* kr = krb + (size_t)k0 * Dn;
        const bf16x8 aK00 = *(const bf16x8*)(kr);
        const bf16x8 aK01 = *(const bf16x8*)(kr + 32);
        const bf16x8 aK10 = *(const bf16x8*)(kr + 16 * Dn);
        const bf16x8 aK11 = *(const bf16x8*)(kr + 16 * Dn + 32);

        // V B-fragments (pre-permuted V^T)
        const u16* vr = vrb + k0;
        const bf16x8 bV0 = *(const bf16x8*)(vr + (size_t)(l16)      * Sn);
        const bf16x8 bV1 = *(const bf16x8*)(vr + (size_t)(16 + l16) * Sn);
        const bf16x8 bV2 = *(const bf16x8*)(vr + (size_t)(32 + l16) * Sn);
        const bf16x8 bV3 = *(const bf16x8*)(vr + (size_t)(48 + l16) * Sn);

        f32x4 s0 = {0.f, 0.f, 0.f, 0.f}, s1 = s0;
        s0 = __builtin_amdgcn_mfma_f32_16x16x32_bf16(aK00, bQ0, s0, 0, 0, 0);
        s0 = __builtin_amdgcn_mfma_f32_16x16x32_bf16(aK01, bQ1, s0, 0, 0, 0);
        s1 = __builtin_amdgcn_mfma_f32_16x16x32_bf16(aK10, bQ0, s1, 0, 0, 0);
        s1 = __builtin_amdgcn_mfma_f32_16x16x32_bf16(aK11, bQ1, s1, 0, 0, 0);

        const float dv0[4] = {pD0[cur].x, pD0[cur].y, pD0[cur].z, pD0[cur].w};
        const float dv1[4] = {pD1[cur].x, pD1[cur].y, pD1[cur].z, pD1[cur].w};
        const float ev0[4] = {pE0[cur].x, pE0[cur].y, pE0[cur].z, pE0[cur].w};
        const float ev1[4] = {pE1[cur].x, pE1[cur].y, pE1[cur].z, pE1[cur].w};
        const int   mv0[4] = {m0.x, m0.y, m0.z, m0.w};
        const int   mv1[4] = {m1.x, m1.y, m1.z, m1.w};

        bf16x8 aP;
#pragma unroll
        for (int r = 0; r < 4; r++) {
            float tf = dv0[r] * invhD;
            int ix = min((int)tf, TN - 1);
            u32 p = sU.tab[ix];
            float b = fmaf(bf2f((u16)(p >> 16)), tf - (float)ix, bf2f((u16)p));
            tf = ev0[r] * invhE;
            ix = min((int)tf, TN - 1);
            p = sU.tab[TN + ix];
            b += fmaf(bf2f((u16)(p >> 16)), tf - (float)ix, bf2f((u16)p));
            b = fminf(fmaxf(b, -60.f), 64.f);
            float v0 = fmaf(s0[r], scale, b);
            v0 = (mv0[r] == 0) ? -60.f : v0;

            tf = dv1[r] * invhD;
            ix = min((int)tf, TN - 1);
            p = sU.tab[ix];
            b = fmaf(bf2f((u16)(p >> 16)), tf - (float)ix, bf2f((u16)p));
            tf = ev1[r] * invhE;
            ix = min((int)tf, TN - 1);
            p = sU.tab[TN + ix];
            b += fmaf(bf2f((u16)(p >> 16)), tf - (float)ix, bf2f((u16)p));
            b = fminf(fmaxf(b, -60.f), 64.f);
            float v1 = fmaf(s1[r], scale, b);
            v1 = (mv1[r] == 0) ? -60.f : v1;

            const float e0 = __expf(v0);
            const float e1 = __expf(v1);
            l_r += e0 + e1;
            aP[r]     = (short)f2bf(e0);
            aP[4 + r] = (short)f2bf(e1);
        }

        O0 = __builtin_amdgcn_mfma_f32_16x16x32_bf16(aP, bV0, O0, 0, 0, 0);
        O1 = __builtin_amdgcn_mfma_f32_16x16x32_bf16(aP, bV1, O1, 0, 0, 0);
        O2 = __builtin_amdgcn_mfma_f32_16x16x32_bf16(aP, bV2, O2, 0, 0, 0);
        O3 = __builtin_amdgcn_mfma_f32_16x16x32_bf16(aP, bV3, O3, 0, 0, 0);
    }

    // l reduction (row = l16, sum across quads) + cross-wave combine
    l_r += __shfl_xor(l_r, 16, 64);
    l_r += __shfl_xor(l_r, 32, 64);
    __syncthreads();                 // table use done; reuse union for epilogue
    if (lane < 16) sU.f.L[wave][lane] = l_r;
#pragma unroll
    for (int r = 0; r < 4; r++) {
        sU.f.O[wave][quad * 4 + r][ 0 + l16] = O0[r];
        sU.f.O[wave][quad * 4 + r][16 + l16] = O1[r];
        sU.f.O[wave][quad * 4 + r][32 + l16] = O2[r];
        sU.f.O[wave][quad * 4 + r][48 + l16] = O3[r];
    }
    __syncthreads();

    // write WG partial: O (16x64, unnormalized) and l (16)
    const int row = tid >> 4;
    const int c4  = (tid & 15) * 4;
    const size_t pidx = ((size_t)ks * Hn + h) * (Sn / 16) + qb;

    float acc[4];
#pragma unroll
    for (int c = 0; c < 4; c++) {
        acc[c] = 0.f;
#pragma unroll
        for (int w = 0; w < 4; w++) acc[c] += sU.f.O[w][row][c4 + c];
    }
    float4 ov = {acc[0], acc[1], acc[2], acc[3]};
    *(float4*)(Opart + (pidx * 16 + row) * Dn + c4) = ov;

    if ((tid & 15) == 0) {
        float lg = 0.f;
#pragma unroll
        for (int w = 0; w < 4; w++) lg += sU.f.L[w][row];
        Lpart[pidx * 16 + row] = lg;
    }
}

// ---------------------------------------------------------------------------
// Kernel D: combine KS partials, normalize, write output.
// ---------------------------------------------------------------------------
__global__ __launch_bounds__(256) void combine_kernel(
    const float* __restrict__ Opart, const float* __restrict__ Lpart,
    float* __restrict__ out)
{
    const int qb  = blockIdx.x;
    const int h   = blockIdx.y;
    const int tid = threadIdx.x;
    const int row = tid >> 4;
    const int c4  = (tid & 15) * 4;

    float acc[4] = {0.f, 0.f, 0.f, 0.f};
    float lg = 0.f;
#pragma unroll
    for (int ks = 0; ks < KS; ks++) {
        const size_t pidx = ((size_t)ks * Hn + h) * (Sn / 16) + qb;
        const float4 o = *(const float4*)(Opart + (pidx * 16 + row) * Dn + c4);
        acc[0] += o.x; acc[1] += o.y; acc[2] += o.z; acc[3] += o.w;
        lg += Lpart[pidx * 16 + row];
    }
    const float inv = 1.0f / lg;
    float4 ov = {acc[0] * inv, acc[1] * inv, acc[2] * inv, acc[3] * inv};
    *(float4*)(out + ((size_t)(h * Sn + qb * 16 + row)) * Dn + c4) = ov;
}

// ---------------------------------------------------------------------------
extern "C" void kernel_launch(void* const* d_in, const int* in_sizes, int n_in,
                              void* d_out, int out_size, void* d_ws, size_t ws_size,
                              hipStream_t stream) {
    const float* Q    = (const float*)d_in[0];
    const float* K    = (const float*)d_in[1];
    const float* V    = (const float*)d_in[2];
    const float* Dm   = (const float*)d_in[3];
    const float* Em   = (const float*)d_in[4];
    const int*   Mask = (const int*)d_in[5];
    const float* muD  = (const float*)d_in[6];
    const float* sgD  = (const float*)d_in[7];
    const float* bD   = (const float*)d_in[8];
    const float* muE  = (const float*)d_in[9];
    const float* sgE  = (const float*)d_in[10];
    const float* bE   = (const float*)d_in[11];
    const float* W1   = (const float*)d_in[12];
    const float* b1   = (const float*)d_in[13];
    const float* W2   = (const float*)d_in[14];
    const float* b2   = (const float*)d_in[15];

    // ws: tab 16 KB | Qb 1 MB | Kb 1 MB | VTi 1 MB | Opart 4.2 MB | Lpart 64 KB
    u32* tab = (u32*)d_ws;
    u16* Qb  = (u16*)((char*)d_ws + 2 * TN * 4);
    u16* Kb  = Qb + (size_t)Hn * Sn * Dn;
    u16* VTi = Kb + (size_t)Hn * Sn * Dn;
    float* Opart = (float*)(VTi + (size_t)Hn * Sn * Dn);
    float* Lpart = Opart + (size_t)KS * Hn * (Sn / 16) * 16 * Dn;

    build_tables_kernel<<<2 * TN / 256, 256, 0, stream>>>(
        muD, sgD, bD, muE, sgE, bE, W1, b1, W2, b2, tab);

    prep_kernel<<<1152, 256, 0, stream>>>(Q, K, V, Qb, Kb, VTi);

    dim3 grid(Sn / 16, Hn, KS);
    attn_part_kernel<<<grid, 256, 0, stream>>>(Qb, Kb, VTi, Dm, Em, Mask, tab,
                                               Opart, Lpart);

    dim3 cgrid(Sn / 16, Hn);
    combine_kernel<<<cgrid, 256, 0, stream>>>(Opart, Lpart, (float*)d_out);
}

// Round 8
// 173.096 us; speedup vs baseline: 1.0473x; 1.0473x over previous
//
#include <hip/hip_runtime.h>
#include <math.h>

// Shapes (fixed by the problem)
#define Hn 8
#define Sn 1024
#define Dn 64
#define KG 10

// Bias tables: dist in [0,10), energy in [0,5)
#define TN 1024
#define RD 10.25f
#define RE 5.125f

// LDS staging geometry: per 128-col tile, 16 rows; DMA writes 1024 B per
// instruction (64 lanes x 16 B) = one row-PAIR; pairs padded to 1040 B so
// consumption reads land on rotated banks.
#define PAIRB 1040
#define SLABB (8 * PAIRB)        // 8320 B per D/E/M slab
#define BUFB  (3 * SLABB)        // 24960 B per buffer (D,E,M)

typedef __attribute__((ext_vector_type(8))) short bf16x8;
typedef __attribute__((ext_vector_type(4))) float f32x4;
typedef unsigned short u16;
typedef unsigned int u32;

__device__ inline float bf2f(u16 u) {
    union { u32 i; float f; } v;
    v.i = ((u32)u) << 16;
    return v.f;
}

__device__ inline u16 f2bf(float f) {
    union { float f; u32 i; } v;
    v.f = f;
    u32 i = v.i;
    return (u16)((i + 0x7FFFu + ((i >> 16) & 1u)) >> 16);   // RNE
}

// async global->LDS DMA, 16 B/lane; lds dest = uniform base + lane*16
__device__ inline void async16(const void* g, void* lds) {
    __builtin_amdgcn_global_load_lds(
        (const __attribute__((address_space(1))) void*)g,
        (__attribute__((address_space(3))) void*)lds, 16, 0, 0);
}

// ---------------------------------------------------------------------------
// RBF (10 gaussians) -> 10x10 MLP (exact gelu) -> scalar, all f32.
// ---------------------------------------------------------------------------
__device__ float bias_eval(float x,
                           const float* __restrict__ mu, const float* __restrict__ sg,
                           const float* __restrict__ bb,
                           const float* __restrict__ W1, const float* __restrict__ b1,
                           const float* __restrict__ W2, const float* __restrict__ b2) {
    const float inv_s2pi = 0.39894228040143267794f;
    float psi[KG];
#pragma unroll
    for (int k = 0; k < KG; k++) {
        float s = sg[k];
        float z = (x + bb[k] - mu[k]) / s;
        psi[k] = __expf(-0.5f * z * z) * (inv_s2pi / s);
    }
    float out = b2[0];
#pragma unroll
    for (int l = 0; l < KG; l++) {
        float a = b1[l];
#pragma unroll
        for (int k = 0; k < KG; k++) a += psi[k] * W1[l * KG + k];
        float g = 0.5f * a * (1.0f + erff(a * 0.70710678118654752440f));
        out += g * W2[l];
    }
    return out;
}

// ---------------------------------------------------------------------------
// Kernel A: interpolation tables. Entry i: lo16 = bf16(f(x_i)),
// hi16 = bf16(f(x_{i+1}) - f(x_i)). [0,TN) dist, [TN,2TN) energy.
// ---------------------------------------------------------------------------
__global__ __launch_bounds__(256) void build_tables_kernel(
    const float* __restrict__ muD, const float* __restrict__ sgD, const float* __restrict__ bD,
    const float* __restrict__ muE, const float* __restrict__ sgE, const float* __restrict__ bE,
    const float* __restrict__ W1, const float* __restrict__ b1,
    const float* __restrict__ W2, const float* __restrict__ b2,
    u32* __restrict__ tab)
{
    int id = blockIdx.x * 256 + threadIdx.x;   // 0 .. 2047
    int which = (id >= TN);
    int idx = id & (TN - 1);
    float h = (which ? RE : RD) / (float)TN;
    float x0 = idx * h;
    float v0, v1;
    if (which) {
        v0 = bias_eval(x0,     muE, sgE, bE, W1, b1, W2, b2);
        v1 = bias_eval(x0 + h, muE, sgE, bE, W1, b1, W2, b2);
    } else {
        v0 = bias_eval(x0,     muD, sgD, bD, W1, b1, W2, b2);
        v1 = bias_eval(x0 + h, muD, sgD, bD, W1, b1, W2, b2);
    }
    tab[id] = (u32)f2bf(v0) | ((u32)f2bf(v1 - v0) << 16);
}

// ---------------------------------------------------------------------------
// Kernel B: small prepass.
//  WGs [0,1024)     : Q,K f32 -> bf16 (float4 granularity).
//  WGs [1024,1152)  : V -> bf16 transpose via LDS tile, layout [h][d][s']
//                     with MFMA k-perm: s' = t*32+q*8+j <-> s = t*32+q*4+(j&3)+16*(j>>2).
// ---------------------------------------------------------------------------
__global__ __launch_bounds__(256) void prep_kernel(
    const float* __restrict__ Q, const float* __restrict__ K, const float* __restrict__ V,
    u16* __restrict__ Qb, u16* __restrict__ Kb, u16* __restrict__ VTi)
{
    __shared__ float tile[64][68];
    const int wg = blockIdx.x, tid = threadIdx.x;

    if (wg < 1024) {
        int i = wg * 256 + tid;                  // 0 .. 262143 float4 units
        int arr = i >> 17;                        // 0 = Q, 1 = K
        i &= (1 << 17) - 1;
        float4 v = ((const float4*)(arr ? K : Q))[i];
        ushort4 o;
        o.x = f2bf(v.x); o.y = f2bf(v.y); o.z = f2bf(v.z); o.w = f2bf(v.w);
        ((ushort4*)(arr ? Kb : Qb))[i] = o;
    } else {
        const int b  = wg - 1024;                // 0..127
        const int h  = b >> 4;
        const int s0 = (b & 15) * 64;
        const int rr = tid >> 4, cc = (tid & 15) * 4;
        const float* Vh = V + ((size_t)h * Sn + s0) * Dn;
#pragma unroll
        for (int i = 0; i < 4; i++) {
            float4 v = *(const float4*)(Vh + (size_t)(i * 16 + rr) * Dn + cc);
            tile[i * 16 + rr][cc]     = v.x;
            tile[i * 16 + rr][cc + 1] = v.y;
            tile[i * 16 + rr][cc + 2] = v.z;
            tile[i * 16 + rr][cc + 3] = v.w;
        }
        __syncthreads();
        u16* dst = VTi + (size_t)h * Dn * Sn + s0;
#pragma unroll
        for (int i = 0; i < 4; i++) {
            const int d = i * 16 + rr;
            u16 tmp[4];
#pragma unroll
            for (int j2 = 0; j2 < 4; j2++) {
                int sp = cc + j2;                // s' in 0..63
                int q = (sp >> 3) & 3, j = sp & 7;
                int s = (sp & ~31) + q * 4 + (j & 3) + ((j >> 2) << 4);
                tmp[j2] = f2bf(tile[s][d]);
            }
            ushort4 o = {tmp[0], tmp[1], tmp[2], tmp[3]};
            *(ushort4*)(dst + (size_t)d * Sn + cc) = o;
        }
    }
}

// ---------------------------------------------------------------------------
// Kernel C: fused attention with DMA-staged D/E/M (m97-style double buffer).
// Grid (S/16, H) = 512 WGs, 256 thr = 4 waves. WG owns 16 q-rows x 1024 cols;
// k-loop = 8 tiles of 128 cols; wave w computes cols [w*32,(w+1)*32) of each.
// Per tile: all 3 streams DMA'd to LDS (24.96 KB, zero VGPR destinations) one
// tile ahead; the only wait is the barrier's implicit vmcnt(0) drain.
// Fixed-max softmax (scores bounded; normalization cancels).
// LDS: 2 x 24960 buffer (union w/ epilogue) + 8 KB tables = 58.1 KB -> 2 WG/CU.
// ---------------------------------------------------------------------------
__global__ __launch_bounds__(256, 2) void attn_kernel(
    const u16* __restrict__ Qb, const u16* __restrict__ Kb, const u16* __restrict__ VTi,
    const float* __restrict__ Dm, const float* __restrict__ Em, const int* __restrict__ Mk,
    const u32* __restrict__ gtab, float* __restrict__ out)
{
    __shared__ __align__(16) union {
        char buf[2][BUFB];                                   // staging buffers
        struct { float O[4][16][68]; float L[4][16]; } f;    // epilogue (17.7 KB)
    } sB;
    __shared__ __align__(16) u32 sTab[2 * TN];               // 8 KB

    const int tid  = threadIdx.x;
    const int h    = blockIdx.y;
    const int q0   = blockIdx.x * 16;
    const int wave = tid >> 6;
    const int lane = tid & 63;
    const int quad = lane >> 4;
    const int l16  = lane & 15;

    {   // stage tables: 512 uint4 over 256 threads
        const uint4* g4 = (const uint4*)gtab;
        uint4* s4 = (uint4*)sTab;
        s4[tid] = g4[tid];
        s4[tid + 256] = g4[tid + 256];
    }

    // global origins of this WG's 16-row slab
    const size_t rb = ((size_t)h * Sn + q0) * Sn;
    const float* Dg = Dm + rb;
    const float* Eg = Em + rb;
    const int*   Mg = Mk + rb;

    // per-lane DMA source mapping: one instr = one row-pair (2 x 512 B)
    const int drow = lane >> 5;              // 0/1 within pair
    const int dcol = (lane & 31) * 4;        // float index within row half

    // wave w stages pairs {2w, 2w+1} of each slab (rows 4w..4w+3)
    auto stage = [&](int t, int b) {
        char* bb = sB.buf[b];
#pragma unroll
        for (int pp = 0; pp < 2; pp++) {
            const int p = wave * 2 + pp;
            const size_t go = (size_t)(2 * p + drow) * Sn + (size_t)t * 128 + dcol;
            async16(Dg + go, bb + (size_t)p * PAIRB);
            async16(Eg + go, bb + SLABB + (size_t)p * PAIRB);
            async16(Mg + go, bb + 2 * SLABB + (size_t)p * PAIRB);
        }
    };

    const u16* Qh = Qb  + (size_t)h * Sn * Dn;
    const u16* Kh = Kb  + (size_t)h * Sn * Dn;
    const u16* Vh = VTi + (size_t)h * Dn * Sn;
    const float invhD = (float)TN / RD;
    const float invhE = (float)TN / RE;
    const float scale = 0.08838834764831845f;    // 1/sqrt(2*64)

    // Persistent Q B-fragments: B[n=l16][k=quad*8+j]
    const bf16x8 bQ0 = *(const bf16x8*)(Qh + (q0 + l16) * Dn + quad * 8);
    const bf16x8 bQ1 = *(const bf16x8*)(Qh + (q0 + l16) * Dn + 32 + quad * 8);

    f32x4 O0 = {0.f, 0.f, 0.f, 0.f}, O1 = O0, O2 = O0, O3 = O0;
    float l_r = 0.f;

    const u16* krb = Kh + (size_t)l16 * Dn + quad * 8;
    const u16* vrb = Vh + quad * 8;

    // consumption offsets within a staged slab (row = l16, cols = wave slice)
    const int co = (wave * 32 + quad * 4) * 4;
    const int ro = (l16 >> 1) * PAIRB + (l16 & 1) * 512;

    stage(0, 0);
    __syncthreads();     // drains DMA(0) + table ds_writes

#pragma unroll
    for (int t = 0; t < 8; t++) {
        if (t < 7) stage(t + 1, (t + 1) & 1);

        const int k0 = t * 128 + wave * 32;

        // K A-fragments + V B-fragments (small, L2-resident)
        const u16* kr = krb + (size_t)k0 * Dn;
        const bf16x8 aK00 = *(const bf16x8*)(kr);
        const bf16x8 aK01 = *(const bf16x8*)(kr + 32);
        const bf16x8 aK10 = *(const bf16x8*)(kr + 16 * Dn);
        const bf16x8 aK11 = *(const bf16x8*)(kr + 16 * Dn + 32);
        const u16* vr = vrb + k0;
        const bf16x8 bV0 = *(const bf16x8*)(vr + (size_t)(l16)      * Sn);
        const bf16x8 bV1 = *(const bf16x8*)(vr + (size_t)(16 + l16) * Sn);
        const bf16x8 bV2 = *(const bf16x8*)(vr + (size_t)(32 + l16) * Sn);
        const bf16x8 bV3 = *(const bf16x8*)(vr + (size_t)(48 + l16) * Sn);

        // staged D/E/M for this tile (LDS, S^T accumulator layout)
        const char* bb = sB.buf[t & 1];
        const float4 Dv0 = *(const float4*)(bb + ro + co);
        const float4 Dv1 = *(const float4*)(bb + ro + co + 64);
        const float4 Ev0 = *(const float4*)(bb + SLABB + ro + co);
        const float4 Ev1 = *(const float4*)(bb + SLABB + ro + co + 64);
        const int4   Mv0 = *(const int4*)(bb + 2 * SLABB + ro + co);
        const int4   Mv1 = *(const int4*)(bb + 2 * SLABB + ro + co + 64);

        f32x4 s0 = {0.f, 0.f, 0.f, 0.f}, s1 = s0;
        s0 = __builtin_amdgcn_mfma_f32_16x16x32_bf16(aK00, bQ0, s0, 0, 0, 0);
        s0 = __builtin_amdgcn_mfma_f32_16x16x32_bf16(aK01, bQ1, s0, 0, 0, 0);
        s1 = __builtin_amdgcn_mfma_f32_16x16x32_bf16(aK10, bQ0, s1, 0, 0, 0);
        s1 = __builtin_amdgcn_mfma_f32_16x16x32_bf16(aK11, bQ1, s1, 0, 0, 0);

        const float dv0[4] = {Dv0.x, Dv0.y, Dv0.z, Dv0.w};
        const float dv1[4] = {Dv1.x, Dv1.y, Dv1.z, Dv1.w};
        const float ev0[4] = {Ev0.x, Ev0.y, Ev0.z, Ev0.w};
        const float ev1[4] = {Ev1.x, Ev1.y, Ev1.z, Ev1.w};
        const int   mv0[4] = {Mv0.x, Mv0.y, Mv0.z, Mv0.w};
        const int   mv1[4] = {Mv1.x, Mv1.y, Mv1.z, Mv1.w};

        bf16x8 aP;
#pragma unroll
        for (int r = 0; r < 4; r++) {
            float tf = dv0[r] * invhD;
            int ix = min((int)tf, TN - 1);
            u32 p = sTab[ix];
            float b = fmaf(bf2f((u16)(p >> 16)), tf - (float)ix, bf2f((u16)p));
            tf = ev0[r] * invhE;
            ix = min((int)tf, TN - 1);
            p = sTab[TN + ix];
            b += fmaf(bf2f((u16)(p >> 16)), tf - (float)ix, bf2f((u16)p));
            b = fminf(fmaxf(b, -60.f), 64.f);
            float v0 = fmaf(s0[r], scale, b);
            v0 = (mv0[r] == 0) ? -60.f : v0;

            tf = dv1[r] * invhD;
            ix = min((int)tf, TN - 1);
            p = sTab[ix];
            b = fmaf(bf2f((u16)(p >> 16)), tf - (float)ix, bf2f((u16)p));
            tf = ev1[r] * invhE;
            ix = min((int)tf, TN - 1);
            p = sTab[TN + ix];
            b += fmaf(bf2f((u16)(p >> 16)), tf - (float)ix, bf2f((u16)p));
            b = fminf(fmaxf(b, -60.f), 64.f);
            float v1 = fmaf(s1[r], scale, b);
            v1 = (mv1[r] == 0) ? -60.f : v1;

            const float e0 = __expf(v0);
            const float e1 = __expf(v1);
            l_r += e0 + e1;
            aP[r]     = (short)f2bf(e0);
            aP[4 + r] = (short)f2bf(e1);
        }

        O0 = __builtin_amdgcn_mfma_f32_16x16x32_bf16(aP, bV0, O0, 0, 0, 0);
        O1 = __builtin_amdgcn_mfma_f32_16x16x32_bf16(aP, bV1, O1, 0, 0, 0);
        O2 = __builtin_amdgcn_mfma_f32_16x16x32_bf16(aP, bV2, O2, 0, 0, 0);
        O3 = __builtin_amdgcn_mfma_f32_16x16x32_bf16(aP, bV3, O3, 0, 0, 0);

        __syncthreads();   // drains stage(t+1); releases buf[t&1] for t+2
    }

    // l reduction (row = l16, sum across quads) + cross-wave combine
    l_r += __shfl_xor(l_r, 16, 64);
    l_r += __shfl_xor(l_r, 32, 64);
    if (lane < 16) sB.f.L[wave][lane] = l_r;
#pragma unroll
    for (int r = 0; r < 4; r++) {
        sB.f.O[wave][quad * 4 + r][ 0 + l16] = O0[r];
        sB.f.O[wave][quad * 4 + r][16 + l16] = O1[r];
        sB.f.O[wave][quad * 4 + r][32 + l16] = O2[r];
        sB.f.O[wave][quad * 4 + r][48 + l16] = O3[r];
    }
    __syncthreads();

    const int row = tid >> 4;
    const int c4  = (tid & 15) * 4;
    float lg = 0.f;
#pragma unroll
    for (int w = 0; w < 4; w++) lg += sB.f.L[w][row];
    const float inv = 1.0f / lg;

    float acc[4];
#pragma unroll
    for (int c = 0; c < 4; c++) {
        acc[c] = 0.f;
#pragma unroll
        for (int w = 0; w < 4; w++) acc[c] += sB.f.O[w][row][c4 + c];
        acc[c] *= inv;
    }
    float4 ov = {acc[0], acc[1], acc[2], acc[3]};
    *(float4*)(out + ((size_t)(h * Sn + q0 + row)) * Dn + c4) = ov;
}

// ---------------------------------------------------------------------------
extern "C" void kernel_launch(void* const* d_in, const int* in_sizes, int n_in,
                              void* d_out, int out_size, void* d_ws, size_t ws_size,
                              hipStream_t stream) {
    const float* Q    = (const float*)d_in[0];
    const float* K    = (const float*)d_in[1];
    const float* V    = (const float*)d_in[2];
    const float* Dm   = (const float*)d_in[3];
    const float* Em   = (const float*)d_in[4];
    const int*   Mask = (const int*)d_in[5];
    const float* muD  = (const float*)d_in[6];
    const float* sgD  = (const float*)d_in[7];
    const float* bD   = (const float*)d_in[8];
    const float* muE  = (const float*)d_in[9];
    const float* sgE  = (const float*)d_in[10];
    const float* bE   = (const float*)d_in[11];
    const float* W1   = (const float*)d_in[12];
    const float* b1   = (const float*)d_in[13];
    const float* W2   = (const float*)d_in[14];
    const float* b2   = (const float*)d_in[15];

    // ws: tab 8 KB | Qb 1 MB | Kb 1 MB | VTi 1 MB
    u32* tab = (u32*)d_ws;
    u16* Qb  = (u16*)((char*)d_ws + 2 * TN * 4);
    u16* Kb  = Qb + (size_t)Hn * Sn * Dn;
    u16* VTi = Kb + (size_t)Hn * Sn * Dn;

    build_tables_kernel<<<2 * TN / 256, 256, 0, stream>>>(
        muD, sgD, bD, muE, sgE, bE, W1, b1, W2, b2, tab);

    prep_kernel<<<1152, 256, 0, stream>>>(Q, K, V, Qb, Kb, VTi);

    dim3 grid(Sn / 16, Hn);
    attn_kernel<<<grid, 256, 0, stream>>>(Qb, Kb, VTi, Dm, Em, Mask, tab,
                                          (float*)d_out);
}